// Round 15
// baseline (151.524 us; speedup 1.0000x reference)
//
#include <hip/hip_runtime.h>
#include <hip/hip_fp16.h>

#define DEV __device__ __forceinline__

typedef _Float16 f16x8 __attribute__((ext_vector_type(8)));
typedef _Float16 f16x4 __attribute__((ext_vector_type(4)));
typedef float f32x4 __attribute__((ext_vector_type(4)));

DEV void gload16(void* lds, const void* g) {
  __builtin_amdgcn_global_load_lds((__attribute__((address_space(1))) const void*)g,
                                   (__attribute__((address_space(3))) void*)lds,
                                   16, 0, 0);
}

DEV f32x4 mfma16(f16x8 a, f16x8 b, f32x4 c) {
  return __builtin_amdgcn_mfma_f32_16x16x32_f16(a, b, c, 0, 0, 0);
}

DEV f16x8 cvt8(float4 a, float4 b) {
  f16x8 o;
  o[0] = (_Float16)a.x; o[1] = (_Float16)a.y; o[2] = (_Float16)a.z; o[3] = (_Float16)a.w;
  o[4] = (_Float16)b.x; o[5] = (_Float16)b.y; o[6] = (_Float16)b.z; o[7] = (_Float16)b.w;
  return o;
}

// ---------------- fused preprocessing: one dispatch, 3 phases ----------------
// blocks [0,4096):    transpose+cast Wq/Wk/Wv/Wo -> Wt[n][k] f16
// blocks [4096,6144): stream-cast weight fp32 -> Wh f16 (q-major)
// blocks [6144,12288): stream-cast q,k,v fp32 -> Ah f16
__global__ __launch_bounds__(256) void prep_kernel(
    const float* __restrict__ W0, const float* __restrict__ W1,
    const float* __restrict__ W2, const float* __restrict__ W3,
    const float* __restrict__ weight, const float* __restrict__ q,
    const float* __restrict__ k, const float* __restrict__ v,
    _Float16* __restrict__ Wt, _Float16* __restrict__ Wh,
    _Float16* __restrict__ Ah) {
  __shared__ float tile[32][33];
  const int i = blockIdx.x;
  if (i < 4096) {
    const int z = i >> 10, bb = i & 1023;
    const float* W = (z == 0) ? W0 : (z == 1) ? W1 : (z == 2) ? W2 : W3;
    _Float16* dst = Wt + (size_t)z * (1024 * 1024);
    const int tx = threadIdx.x & 31, ty = threadIdx.x >> 5;
    const int n0 = (bb & 31) * 32, k0 = (bb >> 5) * 32;
#pragma unroll
    for (int r = 0; r < 4; ++r)
      tile[ty + r * 8][tx] = W[(size_t)(k0 + ty + r * 8) * 1024 + n0 + tx];
    __syncthreads();
#pragma unroll
    for (int r = 0; r < 4; ++r)
      dst[(size_t)(n0 + ty + r * 8) * 1024 + k0 + tx] = (_Float16)tile[tx][ty + r * 8];
  } else if (i < 6144) {
    const size_t j = (size_t)(i - 4096) * 256 + threadIdx.x;
    float4 a = *(const float4*)(weight + j * 8);
    float4 b = *(const float4*)(weight + j * 8 + 4);
    *(f16x8*)(Wh + j * 8) = cvt8(a, b);
  } else {
    const int j = i - 6144;
    const int y = j >> 11, x = j & 2047;
    const float* src = (y == 0) ? q : (y == 1) ? k : v;
    _Float16* dst = Ah + (size_t)y * (4096ull * 1024);
    const size_t idx = ((size_t)x * 256 + threadIdx.x) * 8;
    float4 a = *(const float4*)(src + idx);
    float4 b = *(const float4*)(src + idx + 4);
    *(f16x8*)(dst + idx) = cvt8(a, b);
  }
}

// ---------------- shared GEMM core: C = A(MxK) @ Bt(N,K)^T ----------------
template <int BM, bool AF32>
DEV void gemm_core(const void* __restrict__ Aptr, const _Float16* __restrict__ Bt,
                   _Float16* Al, _Float16* Bl, int m0, int n0,
                   f32x4 (&acc)[4][4]) {
  constexpr int AS = AF32 ? 40 : 32;
  constexpr int WR = BM / 64, WC = 4 / WR, NI = (128 / WC) / 16;
  const int t = threadIdx.x;
  const int l = t & 63, w = t >> 6;
  const int wr = (WR == 2) ? (w >> 1) : 0;
  const int wc = (WR == 2) ? (w & 1) : w;
  const int lo = l & 15, lg = l >> 4;

  for (int ks = 0; ks < 1024; ks += 32) {
    __syncthreads();
    gload16(&Bl[t * 8], Bt + (size_t)(n0 + (t >> 2)) * 1024 + ks + (t & 3) * 8);
    gload16(&Bl[(t + 256) * 8], Bt + (size_t)(n0 + (t >> 2) + 64) * 1024 + ks + (t & 3) * 8);
    if constexpr (AF32) {
      const float* Ag = (const float*)Aptr;
      const int row = t >> 1, c0 = (t & 1) * 16;
      const float4* src = (const float4*)(Ag + (size_t)(m0 + row) * 1024 + ks + c0);
      float4 f0 = src[0], f1 = src[1], f2 = src[2], f3 = src[3];
      *(f16x8*)&Al[row * AS + c0] = cvt8(f0, f1);
      *(f16x8*)&Al[row * AS + c0 + 8] = cvt8(f2, f3);
    } else {
      const _Float16* Ag = (const _Float16*)Aptr;
      gload16(&Al[t * 8], Ag + (size_t)(m0 + (t >> 2)) * 1024 + ks + (t & 3) * 8);
      if constexpr (BM == 128)
        gload16(&Al[(t + 256) * 8], Ag + (size_t)(m0 + (t >> 2) + 64) * 1024 + ks + (t & 3) * 8);
    }
    __syncthreads();

    f16x8 af[4], bf[NI];
#pragma unroll
    for (int mi = 0; mi < 4; ++mi)
      af[mi] = *(const f16x8*)&Al[(wr * 64 + mi * 16 + lo) * AS + lg * 8];
#pragma unroll
    for (int ni = 0; ni < NI; ++ni)
      bf[ni] = *(const f16x8*)&Bl[(wc * (NI * 16) + ni * 16 + lo) * 32 + lg * 8];
#pragma unroll
    for (int mi = 0; mi < 4; ++mi)
#pragma unroll
      for (int ni = 0; ni < NI; ++ni)
        acc[mi][ni] = mfma16(af[mi], bf[ni], acc[mi][ni]);
  }
}

// ---------------- fused QKV projections, XCD-chunked swizzle ----------------
// BM x 128 tiles; grid (8, 4096/BM, 3).  AHALF: f16 A via global_load_lds.
template <int BM, bool AHALF>
__global__ __launch_bounds__(256) void proj_kernel(
    const _Float16* __restrict__ Ah, const float* __restrict__ qin,
    const float* __restrict__ kin, const float* __restrict__ vin,
    const _Float16* __restrict__ Wt, const float* __restrict__ bq,
    const float* __restrict__ bk, const float* __restrict__ bv,
    _Float16* __restrict__ Qh, _Float16* __restrict__ Kt,
    _Float16* __restrict__ Vt) {
  __shared__ __attribute__((aligned(16))) _Float16 Al[BM * 40];
  __shared__ __attribute__((aligned(16))) _Float16 Bl[128 * 32];
  constexpr int NWG_Z = (4096 / BM) * 8;
  constexpr int CHUNK = (3 * NWG_Z) / 8;   // XCD-bijective: nwg % 8 == 0
  const int lin = blockIdx.x + (blockIdx.y << 3) + blockIdx.z * NWG_Z;
  const int work = (lin & 7) * CHUNK + (lin >> 3);
  const int z = work / NWG_Z;
  const int rem = work % NWG_Z;
  const int m0 = (rem >> 3) * BM;
  const int n0 = (rem & 7) * 128;

  const _Float16* Bt = Wt + (size_t)z * (1 << 20);
  const float* bias = (z == 0) ? bq : (z == 1) ? bk : bv;
  _Float16* C = (z == 0) ? Qh : (z == 1) ? Kt : Vt;

  f32x4 acc[4][4];
#pragma unroll
  for (int i = 0; i < 4; ++i)
#pragma unroll
    for (int j = 0; j < 4; ++j) acc[i][j] = (f32x4){0.f, 0.f, 0.f, 0.f};
  if constexpr (AHALF) {
    gemm_core<BM, false>(Ah + (size_t)z * (4096ull * 1024), Bt, Al, Bl, m0, n0, acc);
  } else {
    const float* A = (z == 0) ? qin : (z == 1) ? kin : vin;
    gemm_core<BM, true>(A, Bt, Al, Bl, m0, n0, acc);
  }

  constexpr int WR = BM / 64, WC = 4 / WR, NI = (128 / WC) / 16;
  const int l = threadIdx.x & 63, w = threadIdx.x >> 6;
  const int wr = (WR == 2) ? (w >> 1) : 0;
  const int wc = (WR == 2) ? (w & 1) : w;
  const int lo = l & 15, lg = l >> 4;
#pragma unroll
  for (int mi = 0; mi < 4; ++mi) {
#pragma unroll
    for (int ni = 0; ni < NI; ++ni) {
      const int col = n0 + wc * (NI * 16) + ni * 16 + lo;
      const int rowb = m0 + wr * 64 + mi * 16 + lg * 4;
      const float bc = bias[col];
      const int h = col >> 6, d = col & 63;
#pragma unroll
      for (int r = 0; r < 4; ++r) {
        const float vv = acc[mi][ni][r] + bc;
        const int m = rowb + r;
        const int b = m >> 10, s = m & 1023;
        const size_t slab = (size_t)(b * 16 + h) * 65536;
        if (z == 0) {
          C[slab + (size_t)s * 64 + d] = (_Float16)vv;
        } else if (z == 1) {
          // K tile: row = s&63, elem d at 16B slot (d>>3)^(row&7)
          C[slab + (size_t)(s >> 6) * 4096 + (size_t)(s & 63) * 64 +
            (((d >> 3) ^ (s & 7)) << 3) + (d & 7)] = (_Float16)vv;
        } else {
          // V^T tile: row = d, col c = s&63 at slot (c>>3)^(d&7)
          C[slab + (size_t)(s >> 6) * 4096 + (size_t)d * 64 +
            ((((s >> 3) & 7) ^ (d & 7)) << 3) + (s & 7)] = (_Float16)vv;
        }
      }
    }
  }
}

// ---------------- output projection: out(f32) = AO @ Wo^T + bo ----------------
__global__ __launch_bounds__(256) void outproj_kernel(
    const _Float16* __restrict__ AO, const _Float16* __restrict__ Bt,
    const float* __restrict__ bias, float* __restrict__ out) {
  __shared__ __attribute__((aligned(16))) _Float16 Al[64 * 32];
  __shared__ __attribute__((aligned(16))) _Float16 Bl[128 * 32];
  const int lin = blockIdx.x + (blockIdx.y << 3);
  const int work = (lin & 7) * 64 + (lin >> 3);
  const int m0 = (work >> 3) * 64;
  const int n0 = (work & 7) * 128;
  f32x4 acc[4][4];
#pragma unroll
  for (int i = 0; i < 4; ++i)
#pragma unroll
    for (int j = 0; j < 4; ++j) acc[i][j] = (f32x4){0.f, 0.f, 0.f, 0.f};
  gemm_core<64, false>(AO, Bt, Al, Bl, m0, n0, acc);

  const int l = threadIdx.x & 63, w = threadIdx.x >> 6;
  const int wc = w;  // WR=1, WC=4, NI=2
  const int lo = l & 15, lg = l >> 4;
#pragma unroll
  for (int mi = 0; mi < 4; ++mi) {
#pragma unroll
    for (int ni = 0; ni < 2; ++ni) {
      const int col = n0 + wc * 32 + ni * 16 + lo;
      const int rowb = m0 + mi * 16 + lg * 4;
      const float bc = bias[col];
#pragma unroll
      for (int r = 0; r < 4; ++r)
        out[(size_t)(rowb + r) * 1024 + col] = acc[mi][ni][r] + bc;
    }
  }
}

// ---------------- Flash attention (round-7/12 proven body, NSPLIT=1) ----------------
// K+V double-buffered, ONE barrier/tile, Pl[16][72], q-major scalar bias loads.
__global__ __launch_bounds__(512, 4) void attn_kernel(
    const _Float16* __restrict__ Qh, const _Float16* __restrict__ Kt,
    const _Float16* __restrict__ Vt, const _Float16* __restrict__ Wh,
    const float* __restrict__ mask, _Float16* __restrict__ AO) {
  __shared__ __attribute__((aligned(16))) _Float16 Kl[2][4096];
  __shared__ __attribute__((aligned(16))) _Float16 Vl[2][4096];
  __shared__ __attribute__((aligned(16))) _Float16 Pl[8][16][72];
  const int t = threadIdx.x, l = t & 63, w = t >> 6;
  const int lo = l & 15, lg = l >> 4;
  const int bh = blockIdx.y, b = bh >> 4, h = bh & 15;
  const int q0w = blockIdx.x * 128 + w * 16;
  constexpr float L2E = 1.44269504089f;
  const float scale = 0.1f + (float)h * (9.9f / 15.0f);
  const float cS = 0.125f * L2E;
  const float cW = scale * L2E;
  const float cM = -1e9f * L2E;
  const _Float16* Kslab = Kt + (size_t)bh * 65536;
  const _Float16* Vslab = Vt + (size_t)bh * 65536;
  const _Float16* Wb = Wh + ((size_t)b << 20);
  const float* Mb = mask + (size_t)b * 1024;
  const int qrow = q0w + lg * 4;
  const int sl = lg ^ (lo & 7);

  const f16x8 qf0 = *(const f16x8*)(Qh + (size_t)bh * 65536 + (q0w + lo) * 64 + lg * 8);
  const f16x8 qf1 = *(const f16x8*)(Qh + (size_t)bh * 65536 + (q0w + lo) * 64 + 32 + lg * 8);

  f32x4 oacc[4];
#pragma unroll
  for (int di = 0; di < 4; ++di) oacc[di] = (f32x4){0.f, 0.f, 0.f, 0.f};
  float mrun[4], lsum[4];
#pragma unroll
  for (int r = 0; r < 4; ++r) { mrun[r] = -1e38f; lsum[r] = 0.f; }

  gload16(&Kl[0][t * 8], Kslab + t * 8);
  gload16(&Vl[0][t * 8], Vslab + t * 8);
  __syncthreads();

  for (int it = 0; it < 16; ++it) {
    const int cur = it & 1;
    if (it + 1 < 16) {
      gload16(&Kl[cur ^ 1][t * 8], Kslab + (size_t)(it + 1) * 4096 + t * 8);
      gload16(&Vl[cur ^ 1][t * 8], Vslab + (size_t)(it + 1) * 4096 + t * 8);
    }
    const int kv0 = it * 64;
    const _Float16* Kb = Kl[cur];
    const _Float16* Vb = Vl[cur];

    float sv[4][4];
    float tm[4] = {-1e38f, -1e38f, -1e38f, -1e38f};
#pragma unroll
    for (int ni = 0; ni < 4; ++ni) {
      const int key = kv0 + ni * 16 + lo;
      const float mkv = Mb[key] * cM;
      float wgt[4];
#pragma unroll
      for (int r = 0; r < 4; ++r)
        wgt[r] = (float)Wb[(size_t)(qrow + r) * 1024 + key];
      const int kr = ni * 16 + lo;
      f16x8 kf0 = *(const f16x8*)(Kb + kr * 64 + sl * 8);
      f16x8 kf1 = *(const f16x8*)(Kb + kr * 64 + (sl ^ 4) * 8);
      f32x4 s = (f32x4){0.f, 0.f, 0.f, 0.f};
      s = mfma16(qf0, kf0, s);
      s = mfma16(qf1, kf1, s);
#pragma unroll
      for (int r = 0; r < 4; ++r) {
        const float x = s[r] * cS + wgt[r] * cW + mkv;  // log2 units
        sv[ni][r] = x;
        tm[r] = fmaxf(tm[r], x);
      }
    }
#pragma unroll
    for (int st = 1; st < 16; st <<= 1)
#pragma unroll
      for (int r = 0; r < 4; ++r) tm[r] = fmaxf(tm[r], __shfl_xor(tm[r], st));
    // defer-max (T13): skip rescale when no row grew its max by > 8 (log2)
    float delta = tm[0] - mrun[0];
#pragma unroll
    for (int r = 1; r < 4; ++r) delta = fmaxf(delta, tm[r] - mrun[r]);
    if (!__all(delta <= 8.0f)) {
      float fr[4];
#pragma unroll
      for (int r = 0; r < 4; ++r) {
        const float mn = fmaxf(mrun[r], tm[r]);
        fr[r] = exp2f(mrun[r] - mn);
        mrun[r] = mn;
        lsum[r] *= fr[r];
      }
#pragma unroll
      for (int di = 0; di < 4; ++di)
#pragma unroll
        for (int r = 0; r < 4; ++r) oacc[di][r] *= fr[r];
    }
#pragma unroll
    for (int ni = 0; ni < 4; ++ni)
#pragma unroll
      for (int r = 0; r < 4; ++r) {
        const float p = exp2f(sv[ni][r] - mrun[r]);
        lsum[r] += p;
        Pl[w][lg * 4 + r][ni * 16 + lo] = (_Float16)p;
      }
    const f16x8 pa0 = *(const f16x8*)(&Pl[w][lo][lg * 8]);
    const f16x8 pa1 = *(const f16x8*)(&Pl[w][lo][32 + lg * 8]);
    __builtin_amdgcn_s_setprio(1);
#pragma unroll
    for (int di = 0; di < 4; ++di) {
      const int d = di * 16 + lo;
      f16x8 vf0 = *(const f16x8*)(Vb + d * 64 + sl * 8);
      f16x8 vf1 = *(const f16x8*)(Vb + d * 64 + (sl ^ 4) * 8);
      oacc[di] = mfma16(pa0, vf0, oacc[di]);
      oacc[di] = mfma16(pa1, vf1, oacc[di]);
    }
    __builtin_amdgcn_s_setprio(0);
    __syncthreads();
  }

#pragma unroll
  for (int st = 1; st < 16; st <<= 1)
#pragma unroll
    for (int r = 0; r < 4; ++r) lsum[r] += __shfl_xor(lsum[r], st);

#pragma unroll
  for (int r = 0; r < 4; ++r) {
    const float inv = 1.0f / lsum[r];
#pragma unroll
    for (int di = 0; di < 4; ++di)
      AO[((size_t)(b * 1024) + qrow + r) * 1024 + h * 64 + di * 16 + lo] =
          (_Float16)(oacc[di][r] * inv);
  }
}

extern "C" void kernel_launch(void* const* d_in, const int* in_sizes, int n_in,
                              void* d_out, int out_size, void* d_ws, size_t ws_size,
                              hipStream_t stream) {
  (void)in_sizes; (void)n_in; (void)out_size;
  const float* v      = (const float*)d_in[0];
  const float* k      = (const float*)d_in[1];
  const float* q      = (const float*)d_in[2];
  const float* weight = (const float*)d_in[3];
  const float* mask   = (const float*)d_in[4];
  const float* Wq = (const float*)d_in[5];
  const float* bq = (const float*)d_in[6];
  const float* Wk = (const float*)d_in[7];
  const float* bk = (const float*)d_in[8];
  const float* Wv = (const float*)d_in[9];
  const float* bv = (const float*)d_in[10];
  const float* Wo = (const float*)d_in[11];
  const float* bo = (const float*)d_in[12];
  float* out = (float*)d_out;

  const size_t MB = 1ull << 20;
  char* ws = (char*)d_ws;
  _Float16* Wt = (_Float16*)ws;                 // 4 x 1M f16 = 8 MB
  _Float16* Qh = (_Float16*)(ws + 8 * MB);      // (B,H,S,64) f16, 8 MB
  _Float16* Kt = (_Float16*)(ws + 16 * MB);     // swizzled K tiles, 8 MB
  _Float16* Vt = (_Float16*)(ws + 24 * MB);     // swizzled V^T tiles, 8 MB
  _Float16* Wh = (_Float16*)(ws + 32 * MB);     // weight f16 (q-major), 8 MB
  _Float16* Ah = (_Float16*)(ws + 40 * MB);     // f16 qkv, 24 MB (dead after proj)
  _Float16* AO = (_Float16*)(ws + 40 * MB);     // attn out, 8 MB (Ah dead by then)

  if (ws_size >= 64 * MB) {
    prep_kernel<<<12288, 256, 0, stream>>>(Wq, Wk, Wv, Wo, weight, q, k, v, Wt, Wh, Ah);
    proj_kernel<128, true><<<dim3(8, 32, 3), 256, 0, stream>>>(Ah, q, k, v, Wt, bq, bk,
                                                               bv, Qh, Kt, Vt);
  } else {
    prep_kernel<<<6144, 256, 0, stream>>>(Wq, Wk, Wv, Wo, weight, q, k, v, Wt, Wh, Ah);
    proj_kernel<128, false><<<dim3(8, 32, 3), 256, 0, stream>>>(nullptr, q, k, v, Wt,
                                                                bq, bk, bv, Qh, Kt, Vt);
  }
  attn_kernel<<<dim3(8, 64), 512, 0, stream>>>(Qh, Kt, Vt, Wh, mask, AO);
  outproj_kernel<<<dim3(8, 64), 256, 0, stream>>>(AO, Wt + 3 * (1 << 20), bo, out);
}

// Round 16
// 139.411 us; speedup vs baseline: 1.0869x; 1.0869x over previous
//
#include <hip/hip_runtime.h>
#include <hip/hip_fp16.h>

#define DEV __device__ __forceinline__

typedef _Float16 f16x8 __attribute__((ext_vector_type(8)));
typedef _Float16 f16x4 __attribute__((ext_vector_type(4)));
typedef float f32x4 __attribute__((ext_vector_type(4)));

DEV void gload16(void* lds, const void* g) {
  __builtin_amdgcn_global_load_lds((__attribute__((address_space(1))) const void*)g,
                                   (__attribute__((address_space(3))) void*)lds,
                                   16, 0, 0);
}

DEV f32x4 mfma16(f16x8 a, f16x8 b, f32x4 c) {
  return __builtin_amdgcn_mfma_f32_16x16x32_f16(a, b, c, 0, 0, 0);
}

DEV f16x8 cvt8(float4 a, float4 b) {
  f16x8 o;
  o[0] = (_Float16)a.x; o[1] = (_Float16)a.y; o[2] = (_Float16)a.z; o[3] = (_Float16)a.w;
  o[4] = (_Float16)b.x; o[5] = (_Float16)b.y; o[6] = (_Float16)b.z; o[7] = (_Float16)b.w;
  return o;
}

// ---------------- fused preprocessing: one dispatch, 3 phases ----------------
// blocks [0,4096):    transpose+cast Wq/Wk/Wv/Wo -> Wt[n][k] f16
// blocks [4096,6144): stream-cast weight fp32 -> Wh f16 (q-major)
// blocks [6144,12288): stream-cast q,k,v fp32 -> Ah f16
__global__ __launch_bounds__(256) void prep_kernel(
    const float* __restrict__ W0, const float* __restrict__ W1,
    const float* __restrict__ W2, const float* __restrict__ W3,
    const float* __restrict__ weight, const float* __restrict__ q,
    const float* __restrict__ k, const float* __restrict__ v,
    _Float16* __restrict__ Wt, _Float16* __restrict__ Wh,
    _Float16* __restrict__ Ah) {
  __shared__ float tile[32][33];
  const int i = blockIdx.x;
  if (i < 4096) {
    const int z = i >> 10, bb = i & 1023;
    const float* W = (z == 0) ? W0 : (z == 1) ? W1 : (z == 2) ? W2 : W3;
    _Float16* dst = Wt + (size_t)z * (1024 * 1024);
    const int tx = threadIdx.x & 31, ty = threadIdx.x >> 5;
    const int n0 = (bb & 31) * 32, k0 = (bb >> 5) * 32;
#pragma unroll
    for (int r = 0; r < 4; ++r)
      tile[ty + r * 8][tx] = W[(size_t)(k0 + ty + r * 8) * 1024 + n0 + tx];
    __syncthreads();
#pragma unroll
    for (int r = 0; r < 4; ++r)
      dst[(size_t)(n0 + ty + r * 8) * 1024 + k0 + tx] = (_Float16)tile[tx][ty + r * 8];
  } else if (i < 6144) {
    const size_t j = (size_t)(i - 4096) * 256 + threadIdx.x;
    float4 a = *(const float4*)(weight + j * 8);
    float4 b = *(const float4*)(weight + j * 8 + 4);
    *(f16x8*)(Wh + j * 8) = cvt8(a, b);
  } else {
    const int j = i - 6144;
    const int y = j >> 11, x = j & 2047;
    const float* src = (y == 0) ? q : (y == 1) ? k : v;
    _Float16* dst = Ah + (size_t)y * (4096ull * 1024);
    const size_t idx = ((size_t)x * 256 + threadIdx.x) * 8;
    float4 a = *(const float4*)(src + idx);
    float4 b = *(const float4*)(src + idx + 4);
    *(f16x8*)(dst + idx) = cvt8(a, b);
  }
}

// ---------------- shared GEMM core: C = A(MxK) @ Bt(N,K)^T ----------------
template <int BM, bool AF32>
DEV void gemm_core(const void* __restrict__ Aptr, const _Float16* __restrict__ Bt,
                   _Float16* Al, _Float16* Bl, int m0, int n0,
                   f32x4 (&acc)[4][4]) {
  constexpr int AS = AF32 ? 40 : 32;
  constexpr int WR = BM / 64, WC = 4 / WR, NI = (128 / WC) / 16;
  const int t = threadIdx.x;
  const int l = t & 63, w = t >> 6;
  const int wr = w / WC, wc = w % WC;
  const int lo = l & 15, lg = l >> 4;

  for (int ks = 0; ks < 1024; ks += 32) {
    __syncthreads();
    gload16(&Bl[t * 8], Bt + (size_t)(n0 + (t >> 2)) * 1024 + ks + (t & 3) * 8);
    gload16(&Bl[(t + 256) * 8], Bt + (size_t)(n0 + (t >> 2) + 64) * 1024 + ks + (t & 3) * 8);
    if constexpr (AF32) {
      const float* Ag = (const float*)Aptr;
      const int row = t >> 1, c0 = (t & 1) * 16;
      const float4* src = (const float4*)(Ag + (size_t)(m0 + row) * 1024 + ks + c0);
      float4 f0 = src[0], f1 = src[1], f2 = src[2], f3 = src[3];
      *(f16x8*)&Al[row * AS + c0] = cvt8(f0, f1);
      *(f16x8*)&Al[row * AS + c0 + 8] = cvt8(f2, f3);
    } else {
      const _Float16* Ag = (const _Float16*)Aptr;
      gload16(&Al[t * 8], Ag + (size_t)(m0 + (t >> 2)) * 1024 + ks + (t & 3) * 8);
      if constexpr (BM == 128)
        gload16(&Al[(t + 256) * 8], Ag + (size_t)(m0 + (t >> 2) + 64) * 1024 + ks + (t & 3) * 8);
    }
    __syncthreads();

    f16x8 af[4], bf[NI];
#pragma unroll
    for (int mi = 0; mi < 4; ++mi)
      af[mi] = *(const f16x8*)&Al[(wr * 64 + mi * 16 + lo) * AS + lg * 8];
#pragma unroll
    for (int ni = 0; ni < NI; ++ni)
      bf[ni] = *(const f16x8*)&Bl[(wc * (NI * 16) + ni * 16 + lo) * 32 + lg * 8];
#pragma unroll
    for (int mi = 0; mi < 4; ++mi)
#pragma unroll
      for (int ni = 0; ni < NI; ++ni)
        acc[mi][ni] = mfma16(af[mi], bf[ni], acc[mi][ni]);
  }
}

// ---------------- fused QKV projections, XCD-chunked swizzle ----------------
template <bool AHALF>
__global__ __launch_bounds__(256) void proj_kernel(
    const _Float16* __restrict__ Ah, const float* __restrict__ qin,
    const float* __restrict__ kin, const float* __restrict__ vin,
    const _Float16* __restrict__ Wt, const float* __restrict__ bq,
    const float* __restrict__ bk, const float* __restrict__ bv,
    _Float16* __restrict__ Qh, _Float16* __restrict__ Kt,
    _Float16* __restrict__ Vt) {
  __shared__ __attribute__((aligned(16))) _Float16 Al[128 * 40];
  __shared__ __attribute__((aligned(16))) _Float16 Bl[128 * 32];
  // XCD-bijective chunked swizzle: nwg=768, 8 XCDs, chunk=96.
  const int lin = blockIdx.x + (blockIdx.y << 3) + (blockIdx.z << 8);
  const int work = (lin & 7) * 96 + (lin >> 3);
  const int z = work >> 8;
  const int m0 = ((work & 255) >> 3) * 128;
  const int n0 = (work & 7) * 128;

  const _Float16* Bt = Wt + (size_t)z * (1 << 20);
  const float* bias = (z == 0) ? bq : (z == 1) ? bk : bv;
  _Float16* C = (z == 0) ? Qh : (z == 1) ? Kt : Vt;

  f32x4 acc[4][4];
#pragma unroll
  for (int i = 0; i < 4; ++i)
#pragma unroll
    for (int j = 0; j < 4; ++j) acc[i][j] = (f32x4){0.f, 0.f, 0.f, 0.f};
  if constexpr (AHALF) {
    gemm_core<128, false>(Ah + (size_t)z * (4096ull * 1024), Bt, Al, Bl, m0, n0, acc);
  } else {
    const float* A = (z == 0) ? qin : (z == 1) ? kin : vin;
    gemm_core<128, true>(A, Bt, Al, Bl, m0, n0, acc);
  }

  const int l = threadIdx.x & 63, w = threadIdx.x >> 6;
  const int wr = w >> 1, wc = w & 1;
  const int lo = l & 15, lg = l >> 4;
#pragma unroll
  for (int mi = 0; mi < 4; ++mi) {
#pragma unroll
    for (int ni = 0; ni < 4; ++ni) {
      const int col = n0 + wc * 64 + ni * 16 + lo;
      const int rowb = m0 + wr * 64 + mi * 16 + lg * 4;
      const float bc = bias[col];
      const int h = col >> 6, d = col & 63;
#pragma unroll
      for (int r = 0; r < 4; ++r) {
        const float vv = acc[mi][ni][r] + bc;
        const int m = rowb + r;
        const int b = m >> 10, s = m & 1023;
        const size_t slab = (size_t)(b * 16 + h) * 65536;
        if (z == 0) {
          C[slab + (size_t)s * 64 + d] = (_Float16)vv;
        } else if (z == 1) {
          // K tile: row = s&63, elem d at 16B slot (d>>3)^(row&7)
          C[slab + (size_t)(s >> 6) * 4096 + (size_t)(s & 63) * 64 +
            (((d >> 3) ^ (s & 7)) << 3) + (d & 7)] = (_Float16)vv;
        } else {
          // V^T tile: row = d, col c = s&63 at slot (c>>3)^(d&7)
          C[slab + (size_t)(s >> 6) * 4096 + (size_t)d * 64 +
            ((((s >> 3) & 7) ^ (d & 7)) << 3) + (s & 7)] = (_Float16)vv;
        }
      }
    }
  }
}

// ---------------- output projection: out(f32) = AO @ Wo^T + bo ----------------
__global__ __launch_bounds__(256) void outproj_kernel(
    const _Float16* __restrict__ AO, const _Float16* __restrict__ Bt,
    const float* __restrict__ bias, float* __restrict__ out) {
  __shared__ __attribute__((aligned(16))) _Float16 Al[64 * 32];
  __shared__ __attribute__((aligned(16))) _Float16 Bl[128 * 32];
  const int lin = blockIdx.x + (blockIdx.y << 3);
  const int work = (lin & 7) * 64 + (lin >> 3);
  const int m0 = (work >> 3) * 64;
  const int n0 = (work & 7) * 128;
  f32x4 acc[4][4];
#pragma unroll
  for (int i = 0; i < 4; ++i)
#pragma unroll
    for (int j = 0; j < 4; ++j) acc[i][j] = (f32x4){0.f, 0.f, 0.f, 0.f};
  gemm_core<64, false>(AO, Bt, Al, Bl, m0, n0, acc);

  const int l = threadIdx.x & 63, w = threadIdx.x >> 6;
  const int wc = w;  // WR=1, WC=4, NI=2
  const int lo = l & 15, lg = l >> 4;
#pragma unroll
  for (int mi = 0; mi < 4; ++mi) {
#pragma unroll
    for (int ni = 0; ni < 2; ++ni) {
      const int col = n0 + wc * 32 + ni * 16 + lo;
      const int rowb = m0 + mi * 16 + lg * 4;
      const float bc = bias[col];
#pragma unroll
      for (int r = 0; r < 4; ++r)
        out[(size_t)(rowb + r) * 1024 + col] = acc[mi][ni][r] + bc;
    }
  }
}

// ---------------- Flash attention (round-7 proven body, verbatim) ----------------
// K+V double-buffered, ONE barrier/tile, Pl[16][72], q-major scalar bias loads.
template <int NSPLIT>
__global__ __launch_bounds__(512, 4) void attn_kernel(
    const _Float16* __restrict__ Qh, const _Float16* __restrict__ Kt,
    const _Float16* __restrict__ Vt, const _Float16* __restrict__ Wh,
    const float* __restrict__ mask, void* __restrict__ Oout,
    float2* __restrict__ Sst) {
  __shared__ __attribute__((aligned(16))) _Float16 Kl[2][4096];
  __shared__ __attribute__((aligned(16))) _Float16 Vl[2][4096];
  __shared__ __attribute__((aligned(16))) _Float16 Pl[8][16][72];
  const int t = threadIdx.x, l = t & 63, w = t >> 6;
  const int lo = l & 15, lg = l >> 4;
  const int bh = blockIdx.y, b = bh >> 4, h = bh & 15;
  const int q0w = blockIdx.x * 128 + w * 16;
  const int sp = (NSPLIT > 1) ? blockIdx.z : 0;
  constexpr int NKT = 16 / NSPLIT;
  const int kt0 = sp * NKT;
  constexpr float L2E = 1.44269504089f;
  const float scale = 0.1f + (float)h * (9.9f / 15.0f);
  const float cS = 0.125f * L2E;
  const float cW = scale * L2E;
  const float cM = -1e9f * L2E;
  const _Float16* Kslab = Kt + (size_t)bh * 65536;
  const _Float16* Vslab = Vt + (size_t)bh * 65536;
  const _Float16* Wb = Wh + ((size_t)b << 20);
  const float* Mb = mask + (size_t)b * 1024;
  const int qrow = q0w + lg * 4;
  const int sl = lg ^ (lo & 7);

  const f16x8 qf0 = *(const f16x8*)(Qh + (size_t)bh * 65536 + (q0w + lo) * 64 + lg * 8);
  const f16x8 qf1 = *(const f16x8*)(Qh + (size_t)bh * 65536 + (q0w + lo) * 64 + 32 + lg * 8);

  f32x4 oacc[4];
#pragma unroll
  for (int di = 0; di < 4; ++di) oacc[di] = (f32x4){0.f, 0.f, 0.f, 0.f};
  float mrun[4], lsum[4];
#pragma unroll
  for (int r = 0; r < 4; ++r) { mrun[r] = -1e38f; lsum[r] = 0.f; }

  gload16(&Kl[0][t * 8], Kslab + (size_t)kt0 * 4096 + t * 8);
  gload16(&Vl[0][t * 8], Vslab + (size_t)kt0 * 4096 + t * 8);
  __syncthreads();

  for (int it = 0; it < NKT; ++it) {
    const int kt = kt0 + it;
    const int cur = it & 1;
    if (it + 1 < NKT) {
      gload16(&Kl[cur ^ 1][t * 8], Kslab + (size_t)(kt + 1) * 4096 + t * 8);
      gload16(&Vl[cur ^ 1][t * 8], Vslab + (size_t)(kt + 1) * 4096 + t * 8);
    }
    const int kv0 = kt * 64;
    const _Float16* Kb = Kl[cur];
    const _Float16* Vb = Vl[cur];

    float sv[4][4];
    float tm[4] = {-1e38f, -1e38f, -1e38f, -1e38f};
#pragma unroll
    for (int ni = 0; ni < 4; ++ni) {
      const int key = kv0 + ni * 16 + lo;
      const float mkv = Mb[key] * cM;
      float wgt[4];
#pragma unroll
      for (int r = 0; r < 4; ++r)
        wgt[r] = (float)Wb[(size_t)(qrow + r) * 1024 + key];
      const int kr = ni * 16 + lo;
      f16x8 kf0 = *(const f16x8*)(Kb + kr * 64 + sl * 8);
      f16x8 kf1 = *(const f16x8*)(Kb + kr * 64 + (sl ^ 4) * 8);
      f32x4 s = (f32x4){0.f, 0.f, 0.f, 0.f};
      s = mfma16(qf0, kf0, s);
      s = mfma16(qf1, kf1, s);
#pragma unroll
      for (int r = 0; r < 4; ++r) {
        const float x = s[r] * cS + wgt[r] * cW + mkv;  // log2 units
        sv[ni][r] = x;
        tm[r] = fmaxf(tm[r], x);
      }
    }
#pragma unroll
    for (int st = 1; st < 16; st <<= 1)
#pragma unroll
      for (int r = 0; r < 4; ++r) tm[r] = fmaxf(tm[r], __shfl_xor(tm[r], st));
    // defer-max (T13): skip rescale when no row grew its max by > 8 (log2)
    float delta = tm[0] - mrun[0];
#pragma unroll
    for (int r = 1; r < 4; ++r) delta = fmaxf(delta, tm[r] - mrun[r]);
    if (!__all(delta <= 8.0f)) {
      float fr[4];
#pragma unroll
      for (int r = 0; r < 4; ++r) {
        const float mn = fmaxf(mrun[r], tm[r]);
        fr[r] = exp2f(mrun[r] - mn);
        mrun[r] = mn;
        lsum[r] *= fr[r];
      }
#pragma unroll
      for (int di = 0; di < 4; ++di)
#pragma unroll
        for (int r = 0; r < 4; ++r) oacc[di][r] *= fr[r];
    }
#pragma unroll
    for (int ni = 0; ni < 4; ++ni)
#pragma unroll
      for (int r = 0; r < 4; ++r) {
        const float p = exp2f(sv[ni][r] - mrun[r]);
        lsum[r] += p;
        Pl[w][lg * 4 + r][ni * 16 + lo] = (_Float16)p;
      }
    const f16x8 pa0 = *(const f16x8*)(&Pl[w][lo][lg * 8]);
    const f16x8 pa1 = *(const f16x8*)(&Pl[w][lo][32 + lg * 8]);
    __builtin_amdgcn_s_setprio(1);
#pragma unroll
    for (int di = 0; di < 4; ++di) {
      const int d = di * 16 + lo;
      f16x8 vf0 = *(const f16x8*)(Vb + d * 64 + sl * 8);
      f16x8 vf1 = *(const f16x8*)(Vb + d * 64 + (sl ^ 4) * 8);
      oacc[di] = mfma16(pa0, vf0, oacc[di]);
      oacc[di] = mfma16(pa1, vf1, oacc[di]);
    }
    __builtin_amdgcn_s_setprio(0);
    __syncthreads();
  }

#pragma unroll
  for (int st = 1; st < 16; st <<= 1)
#pragma unroll
    for (int r = 0; r < 4; ++r) lsum[r] += __shfl_xor(lsum[r], st);

  if constexpr (NSPLIT > 1) {
    if (lo == 0) {
#pragma unroll
      for (int r = 0; r < 4; ++r)
        Sst[(size_t)sp * 65536 + bh * 1024 + qrow + r] = make_float2(mrun[r], lsum[r]);
    }
    _Float16* Op = (_Float16*)Oout + (size_t)sp * (64ull * 1024 * 64);
#pragma unroll
    for (int r = 0; r < 4; ++r) {
      const float inv = 1.0f / lsum[r];
#pragma unroll
      for (int di = 0; di < 4; ++di)
        Op[((size_t)bh * 1024 + qrow + r) * 64 + di * 16 + lo] =
            (_Float16)(oacc[di][r] * inv);
    }
  } else {
    _Float16* AO = (_Float16*)Oout;
#pragma unroll
    for (int r = 0; r < 4; ++r) {
      const float inv = 1.0f / lsum[r];
#pragma unroll
      for (int di = 0; di < 4; ++di)
        AO[((size_t)(b * 1024) + qrow + r) * 1024 + h * 64 + di * 16 + lo] =
            (_Float16)(oacc[di][r] * inv);
    }
  }
}

// keep the r12 kernel set identical: force both instantiations
template __global__ void attn_kernel<1>(const _Float16*, const _Float16*,
                                        const _Float16*, const _Float16*,
                                        const float*, void*, float2*);
template __global__ void attn_kernel<2>(const _Float16*, const _Float16*,
                                        const _Float16*, const _Float16*,
                                        const float*, void*, float2*);

// ---------------- merge two KV-split partials -> AO (B,S,1024) ----------------
__global__ __launch_bounds__(256) void merge_kernel(
    const _Float16* __restrict__ Op, const float2* __restrict__ Sst,
    _Float16* __restrict__ AO) {
  const int idx = blockIdx.x * 256 + threadIdx.x;  // 1M threads, 4 d-elems each
  const int dc = idx & 15;
  const int qq = (idx >> 4) & 1023;
  const int bh = idx >> 14;
  const int b = bh >> 4, h = bh & 15;
  const float2 s1 = Sst[bh * 1024 + qq];
  const float2 s2 = Sst[65536 + bh * 1024 + qq];
  const float m = fmaxf(s1.x, s2.x);
  float w1 = exp2f(s1.x - m) * s1.y;
  float w2 = exp2f(s2.x - m) * s2.y;
  const float inv = 1.f / (w1 + w2);
  w1 *= inv; w2 *= inv;
  const size_t o = ((size_t)bh * 1024 + qq) * 64 + dc * 4;
  const f16x4 o1 = *(const f16x4*)(Op + o);
  const f16x4 o2 = *(const f16x4*)(Op + (64ull * 1024 * 64) + o);
  f16x4 r;
#pragma unroll
  for (int j = 0; j < 4; ++j)
    r[j] = (_Float16)(w1 * (float)o1[j] + w2 * (float)o2[j]);
  *(f16x4*)(AO + ((size_t)(b * 1024 + qq) * 1024 + h * 64 + dc * 4)) = r;
}

extern "C" void kernel_launch(void* const* d_in, const int* in_sizes, int n_in,
                              void* d_out, int out_size, void* d_ws, size_t ws_size,
                              hipStream_t stream) {
  (void)in_sizes; (void)n_in; (void)out_size;
  const float* v      = (const float*)d_in[0];
  const float* k      = (const float*)d_in[1];
  const float* q      = (const float*)d_in[2];
  const float* weight = (const float*)d_in[3];
  const float* mask   = (const float*)d_in[4];
  const float* Wq = (const float*)d_in[5];
  const float* bq = (const float*)d_in[6];
  const float* Wk = (const float*)d_in[7];
  const float* bk = (const float*)d_in[8];
  const float* Wv = (const float*)d_in[9];
  const float* bv = (const float*)d_in[10];
  const float* Wo = (const float*)d_in[11];
  const float* bo = (const float*)d_in[12];
  float* out = (float*)d_out;

  const size_t MB = 1ull << 20;
  char* ws = (char*)d_ws;
  _Float16* Wt = (_Float16*)ws;                 // 4 x 1M f16 = 8 MB
  _Float16* Qh = (_Float16*)(ws + 8 * MB);      // (B,H,S,64) f16, 8 MB
  _Float16* Kt = (_Float16*)(ws + 16 * MB);     // swizzled K tiles, 8 MB
  _Float16* Vt = (_Float16*)(ws + 24 * MB);     // swizzled V^T tiles, 8 MB
  _Float16* Wh = (_Float16*)(ws + 32 * MB);     // weight f16 (q-major), 8 MB
  _Float16* Ah = (_Float16*)(ws + 40 * MB);     // f16 qkv, 24 MB (dead after proj)
  _Float16* AO = (_Float16*)(ws + 40 * MB);     // attn out, 8 MB (Ah dead by then)

  if (ws_size >= 64 * MB) {
    prep_kernel<<<12288, 256, 0, stream>>>(Wq, Wk, Wv, Wo, weight, q, k, v, Wt, Wh, Ah);
    proj_kernel<true><<<dim3(8, 32, 3), 256, 0, stream>>>(Ah, q, k, v, Wt, bq, bk, bv,
                                                          Qh, Kt, Vt);
    attn_kernel<1><<<dim3(8, 64, 1), 512, 0, stream>>>(Qh, Kt, Vt, Wh, mask, AO, nullptr);
    outproj_kernel<<<dim3(8, 64), 256, 0, stream>>>(AO, Wt + 3 * (1 << 20), bo, out);
  } else {
    prep_kernel<<<6144, 256, 0, stream>>>(Wq, Wk, Wv, Wo, weight, q, k, v, Wt, Wh, Ah);
    proj_kernel<false><<<dim3(8, 32, 3), 256, 0, stream>>>(nullptr, q, k, v, Wt, bq, bk,
                                                           bv, Qh, Kt, Vt);
    attn_kernel<1><<<dim3(8, 64, 1), 512, 0, stream>>>(Qh, Kt, Vt, Wh, mask, AO, nullptr);
    outproj_kernel<<<dim3(8, 64), 256, 0, stream>>>(AO, Wt + 3 * (1 << 20), bo, out);
  }
}

// Round 17
// 137.893 us; speedup vs baseline: 1.0989x; 1.0110x over previous
//
#include <hip/hip_runtime.h>
#include <hip/hip_fp16.h>

#define DEV __device__ __forceinline__

typedef _Float16 f16x8 __attribute__((ext_vector_type(8)));
typedef _Float16 f16x4 __attribute__((ext_vector_type(4)));
typedef float f32x4 __attribute__((ext_vector_type(4)));

DEV void gload16(void* lds, const void* g) {
  __builtin_amdgcn_global_load_lds((__attribute__((address_space(1))) const void*)g,
                                   (__attribute__((address_space(3))) void*)lds,
                                   16, 0, 0);
}

DEV f32x4 mfma16(f16x8 a, f16x8 b, f32x4 c) {
  return __builtin_amdgcn_mfma_f32_16x16x32_f16(a, b, c, 0, 0, 0);
}

DEV f16x8 cvt8(float4 a, float4 b) {
  f16x8 o;
  o[0] = (_Float16)a.x; o[1] = (_Float16)a.y; o[2] = (_Float16)a.z; o[3] = (_Float16)a.w;
  o[4] = (_Float16)b.x; o[5] = (_Float16)b.y; o[6] = (_Float16)b.z; o[7] = (_Float16)b.w;
  return o;
}

// ---------------- fused preprocessing: one dispatch, 3 phases ----------------
// blocks [0,4096):    transpose+cast Wq/Wk/Wv/Wo -> Wt[n][k] f16
// blocks [4096,6144): weight fp32 + mask*(-65000) -> Wh f16 (q-major, mask folded)
// blocks [6144,12288): stream-cast q,k,v fp32 -> Ah f16
__global__ __launch_bounds__(256) void prep_kernel(
    const float* __restrict__ W0, const float* __restrict__ W1,
    const float* __restrict__ W2, const float* __restrict__ W3,
    const float* __restrict__ weight, const float* __restrict__ mask,
    const float* __restrict__ q, const float* __restrict__ k,
    const float* __restrict__ v, _Float16* __restrict__ Wt,
    _Float16* __restrict__ Wh, _Float16* __restrict__ Ah) {
  __shared__ float tile[32][33];
  const int i = blockIdx.x;
  if (i < 4096) {
    const int z = i >> 10, bb = i & 1023;
    const float* W = (z == 0) ? W0 : (z == 1) ? W1 : (z == 2) ? W2 : W3;
    _Float16* dst = Wt + (size_t)z * (1024 * 1024);
    const int tx = threadIdx.x & 31, ty = threadIdx.x >> 5;
    const int n0 = (bb & 31) * 32, k0 = (bb >> 5) * 32;
#pragma unroll
    for (int r = 0; r < 4; ++r)
      tile[ty + r * 8][tx] = W[(size_t)(k0 + ty + r * 8) * 1024 + n0 + tx];
    __syncthreads();
#pragma unroll
    for (int r = 0; r < 4; ++r)
      dst[(size_t)(n0 + ty + r * 8) * 1024 + k0 + tx] = (_Float16)tile[tx][ty + r * 8];
  } else if (i < 6144) {
    const size_t j = (size_t)(i - 4096) * 256 + threadIdx.x;  // 8-elem group index
    const size_t e0 = j * 8;
    const int bb = (int)(e0 >> 20);          // batch of this weight element
    const int key0 = (int)(e0 & 1023);       // 1024 % 8 == 0 -> same row for all 8
    float4 a = *(const float4*)(weight + e0);
    float4 b4 = *(const float4*)(weight + e0 + 4);
    const float4 m1 = *(const float4*)(mask + bb * 1024 + key0);
    const float4 m2 = *(const float4*)(mask + bb * 1024 + key0 + 4);
    a.x -= 65000.f * m1.x; a.y -= 65000.f * m1.y;
    a.z -= 65000.f * m1.z; a.w -= 65000.f * m1.w;
    b4.x -= 65000.f * m2.x; b4.y -= 65000.f * m2.y;
    b4.z -= 65000.f * m2.z; b4.w -= 65000.f * m2.w;
    *(f16x8*)(Wh + e0) = cvt8(a, b4);
  } else {
    const int j = i - 6144;
    const int y = j >> 11, x = j & 2047;
    const float* src = (y == 0) ? q : (y == 1) ? k : v;
    _Float16* dst = Ah + (size_t)y * (4096ull * 1024);
    const size_t idx = ((size_t)x * 256 + threadIdx.x) * 8;
    float4 a = *(const float4*)(src + idx);
    float4 b = *(const float4*)(src + idx + 4);
    *(f16x8*)(dst + idx) = cvt8(a, b);
  }
}

// ---------------- shared GEMM core: C = A(MxK) @ Bt(N,K)^T ----------------
template <int BM, bool AF32>
DEV void gemm_core(const void* __restrict__ Aptr, const _Float16* __restrict__ Bt,
                   _Float16* Al, _Float16* Bl, int m0, int n0,
                   f32x4 (&acc)[4][4]) {
  constexpr int AS = AF32 ? 40 : 32;
  constexpr int WR = BM / 64, WC = 4 / WR, NI = (128 / WC) / 16;
  const int t = threadIdx.x;
  const int l = t & 63, w = t >> 6;
  const int wr = w / WC, wc = w % WC;
  const int lo = l & 15, lg = l >> 4;

  for (int ks = 0; ks < 1024; ks += 32) {
    __syncthreads();
    gload16(&Bl[t * 8], Bt + (size_t)(n0 + (t >> 2)) * 1024 + ks + (t & 3) * 8);
    gload16(&Bl[(t + 256) * 8], Bt + (size_t)(n0 + (t >> 2) + 64) * 1024 + ks + (t & 3) * 8);
    if constexpr (AF32) {
      const float* Ag = (const float*)Aptr;
      const int row = t >> 1, c0 = (t & 1) * 16;
      const float4* src = (const float4*)(Ag + (size_t)(m0 + row) * 1024 + ks + c0);
      float4 f0 = src[0], f1 = src[1], f2 = src[2], f3 = src[3];
      *(f16x8*)&Al[row * AS + c0] = cvt8(f0, f1);
      *(f16x8*)&Al[row * AS + c0 + 8] = cvt8(f2, f3);
    } else {
      const _Float16* Ag = (const _Float16*)Aptr;
      gload16(&Al[t * 8], Ag + (size_t)(m0 + (t >> 2)) * 1024 + ks + (t & 3) * 8);
      if constexpr (BM == 128)
        gload16(&Al[(t + 256) * 8], Ag + (size_t)(m0 + (t >> 2) + 64) * 1024 + ks + (t & 3) * 8);
    }
    __syncthreads();

    f16x8 af[4], bf[NI];
#pragma unroll
    for (int mi = 0; mi < 4; ++mi)
      af[mi] = *(const f16x8*)&Al[(wr * 64 + mi * 16 + lo) * AS + lg * 8];
#pragma unroll
    for (int ni = 0; ni < NI; ++ni)
      bf[ni] = *(const f16x8*)&Bl[(wc * (NI * 16) + ni * 16 + lo) * 32 + lg * 8];
#pragma unroll
    for (int mi = 0; mi < 4; ++mi)
#pragma unroll
      for (int ni = 0; ni < NI; ++ni)
        acc[mi][ni] = mfma16(af[mi], bf[ni], acc[mi][ni]);
  }
}

// ---------------- fused QKV projections, XCD-chunked swizzle ----------------
template <bool AHALF>
__global__ __launch_bounds__(256) void proj_kernel(
    const _Float16* __restrict__ Ah, const float* __restrict__ qin,
    const float* __restrict__ kin, const float* __restrict__ vin,
    const _Float16* __restrict__ Wt, const float* __restrict__ bq,
    const float* __restrict__ bk, const float* __restrict__ bv,
    _Float16* __restrict__ Qh, _Float16* __restrict__ Kt,
    _Float16* __restrict__ Vt) {
  __shared__ __attribute__((aligned(16))) _Float16 Al[128 * 40];
  __shared__ __attribute__((aligned(16))) _Float16 Bl[128 * 32];
  // XCD-bijective chunked swizzle: nwg=768, 8 XCDs, chunk=96.
  const int lin = blockIdx.x + (blockIdx.y << 3) + (blockIdx.z << 8);
  const int work = (lin & 7) * 96 + (lin >> 3);
  const int z = work >> 8;
  const int m0 = ((work & 255) >> 3) * 128;
  const int n0 = (work & 7) * 128;

  const _Float16* Bt = Wt + (size_t)z * (1 << 20);
  const float* bias = (z == 0) ? bq : (z == 1) ? bk : bv;
  _Float16* C = (z == 0) ? Qh : (z == 1) ? Kt : Vt;

  f32x4 acc[4][4];
#pragma unroll
  for (int i = 0; i < 4; ++i)
#pragma unroll
    for (int j = 0; j < 4; ++j) acc[i][j] = (f32x4){0.f, 0.f, 0.f, 0.f};
  if constexpr (AHALF) {
    gemm_core<128, false>(Ah + (size_t)z * (4096ull * 1024), Bt, Al, Bl, m0, n0, acc);
  } else {
    const float* A = (z == 0) ? qin : (z == 1) ? kin : vin;
    gemm_core<128, true>(A, Bt, Al, Bl, m0, n0, acc);
  }

  const int l = threadIdx.x & 63, w = threadIdx.x >> 6;
  const int wr = w >> 1, wc = w & 1;
  const int lo = l & 15, lg = l >> 4;
#pragma unroll
  for (int mi = 0; mi < 4; ++mi) {
#pragma unroll
    for (int ni = 0; ni < 4; ++ni) {
      const int col = n0 + wc * 64 + ni * 16 + lo;
      const int rowb = m0 + wr * 64 + mi * 16 + lg * 4;
      const float bc = bias[col];
      const int h = col >> 6, d = col & 63;
#pragma unroll
      for (int r = 0; r < 4; ++r) {
        const float vv = acc[mi][ni][r] + bc;
        const int m = rowb + r;
        const int b = m >> 10, s = m & 1023;
        const size_t slab = (size_t)(b * 16 + h) * 65536;
        if (z == 0) {
          C[slab + (size_t)s * 64 + d] = (_Float16)vv;
        } else if (z == 1) {
          // K tile: row = s&63, elem d at 16B slot (d>>3)^(row&7)
          C[slab + (size_t)(s >> 6) * 4096 + (size_t)(s & 63) * 64 +
            (((d >> 3) ^ (s & 7)) << 3) + (d & 7)] = (_Float16)vv;
        } else {
          // V^T tile: row = d, col c = s&63 at slot (c>>3)^(d&7)
          C[slab + (size_t)(s >> 6) * 4096 + (size_t)d * 64 +
            ((((s >> 3) & 7) ^ (d & 7)) << 3) + (s & 7)] = (_Float16)vv;
        }
      }
    }
  }
}

// ---------------- output projection: out(f32) = AO @ Wo^T + bo ----------------
__global__ __launch_bounds__(256) void outproj_kernel(
    const _Float16* __restrict__ AO, const _Float16* __restrict__ Bt,
    const float* __restrict__ bias, float* __restrict__ out) {
  __shared__ __attribute__((aligned(16))) _Float16 Al[64 * 32];
  __shared__ __attribute__((aligned(16))) _Float16 Bl[128 * 32];
  const int lin = blockIdx.x + (blockIdx.y << 3);
  const int work = (lin & 7) * 64 + (lin >> 3);
  const int m0 = (work >> 3) * 64;
  const int n0 = (work & 7) * 128;
  f32x4 acc[4][4];
#pragma unroll
  for (int i = 0; i < 4; ++i)
#pragma unroll
    for (int j = 0; j < 4; ++j) acc[i][j] = (f32x4){0.f, 0.f, 0.f, 0.f};
  gemm_core<64, false>(AO, Bt, Al, Bl, m0, n0, acc);

  const int l = threadIdx.x & 63, w = threadIdx.x >> 6;
  const int wc = w;  // WR=1, WC=4, NI=2
  const int lo = l & 15, lg = l >> 4;
#pragma unroll
  for (int mi = 0; mi < 4; ++mi) {
#pragma unroll
    for (int ni = 0; ni < 2; ++ni) {
      const int col = n0 + wc * 32 + ni * 16 + lo;
      const int rowb = m0 + mi * 16 + lg * 4;
      const float bc = bias[col];
#pragma unroll
      for (int r = 0; r < 4; ++r)
        out[(size_t)(rowb + r) * 1024 + col] = acc[mi][ni][r] + bc;
    }
  }
}

// ---------------- Flash attention (r16 body; mask folded into Wh) ----------------
// K+V double-buffered, ONE barrier/tile, Pl[16][72], q-major scalar bias loads.
template <int NSPLIT>
__global__ __launch_bounds__(512, 4) void attn_kernel(
    const _Float16* __restrict__ Qh, const _Float16* __restrict__ Kt,
    const _Float16* __restrict__ Vt, const _Float16* __restrict__ Wh,
    const float* __restrict__ mask, void* __restrict__ Oout,
    float2* __restrict__ Sst) {
  __shared__ __attribute__((aligned(16))) _Float16 Kl[2][4096];
  __shared__ __attribute__((aligned(16))) _Float16 Vl[2][4096];
  __shared__ __attribute__((aligned(16))) _Float16 Pl[8][16][72];
  const int t = threadIdx.x, l = t & 63, w = t >> 6;
  const int lo = l & 15, lg = l >> 4;
  const int bh = blockIdx.y, b = bh >> 4, h = bh & 15;
  const int q0w = blockIdx.x * 128 + w * 16;
  const int sp = (NSPLIT > 1) ? blockIdx.z : 0;
  constexpr int NKT = 16 / NSPLIT;
  const int kt0 = sp * NKT;
  constexpr float L2E = 1.44269504089f;
  const float scale = 0.1f + (float)h * (9.9f / 15.0f);
  const float cS = 0.125f * L2E;
  const float cW = scale * L2E;
  (void)mask;
  const _Float16* Kslab = Kt + (size_t)bh * 65536;
  const _Float16* Vslab = Vt + (size_t)bh * 65536;
  const _Float16* Wb = Wh + ((size_t)b << 20);
  const int qrow = q0w + lg * 4;
  const int sl = lg ^ (lo & 7);

  const f16x8 qf0 = *(const f16x8*)(Qh + (size_t)bh * 65536 + (q0w + lo) * 64 + lg * 8);
  const f16x8 qf1 = *(const f16x8*)(Qh + (size_t)bh * 65536 + (q0w + lo) * 64 + 32 + lg * 8);

  f32x4 oacc[4];
#pragma unroll
  for (int di = 0; di < 4; ++di) oacc[di] = (f32x4){0.f, 0.f, 0.f, 0.f};
  float mrun[4], lsum[4];
#pragma unroll
  for (int r = 0; r < 4; ++r) { mrun[r] = -1e38f; lsum[r] = 0.f; }

  gload16(&Kl[0][t * 8], Kslab + (size_t)kt0 * 4096 + t * 8);
  gload16(&Vl[0][t * 8], Vslab + (size_t)kt0 * 4096 + t * 8);
  __syncthreads();

  for (int it = 0; it < NKT; ++it) {
    const int kt = kt0 + it;
    const int cur = it & 1;
    if (it + 1 < NKT) {
      gload16(&Kl[cur ^ 1][t * 8], Kslab + (size_t)(kt + 1) * 4096 + t * 8);
      gload16(&Vl[cur ^ 1][t * 8], Vslab + (size_t)(kt + 1) * 4096 + t * 8);
    }
    const int kv0 = kt * 64;
    const _Float16* Kb = Kl[cur];
    const _Float16* Vb = Vl[cur];

    float sv[4][4];
    float tm[4] = {-1e38f, -1e38f, -1e38f, -1e38f};
#pragma unroll
    for (int ni = 0; ni < 4; ++ni) {
      const int key = kv0 + ni * 16 + lo;
      float wgt[4];
#pragma unroll
      for (int r = 0; r < 4; ++r)
        wgt[r] = (float)Wb[(size_t)(qrow + r) * 1024 + key];
      const int kr = ni * 16 + lo;
      f16x8 kf0 = *(const f16x8*)(Kb + kr * 64 + sl * 8);
      f16x8 kf1 = *(const f16x8*)(Kb + kr * 64 + (sl ^ 4) * 8);
      f32x4 s = (f32x4){0.f, 0.f, 0.f, 0.f};
      s = mfma16(qf0, kf0, s);
      s = mfma16(qf1, kf1, s);
#pragma unroll
      for (int r = 0; r < 4; ++r) {
        const float x = s[r] * cS + wgt[r] * cW;  // log2 units; mask pre-folded
        sv[ni][r] = x;
        tm[r] = fmaxf(tm[r], x);
      }
    }
#pragma unroll
    for (int st = 1; st < 16; st <<= 1)
#pragma unroll
      for (int r = 0; r < 4; ++r) tm[r] = fmaxf(tm[r], __shfl_xor(tm[r], st));
    // defer-max (T13): skip rescale when no row grew its max by > 8 (log2)
    float delta = tm[0] - mrun[0];
#pragma unroll
    for (int r = 1; r < 4; ++r) delta = fmaxf(delta, tm[r] - mrun[r]);
    if (!__all(delta <= 8.0f)) {
      float fr[4];
#pragma unroll
      for (int r = 0; r < 4; ++r) {
        const float mn = fmaxf(mrun[r], tm[r]);
        fr[r] = exp2f(mrun[r] - mn);
        mrun[r] = mn;
        lsum[r] *= fr[r];
      }
#pragma unroll
      for (int di = 0; di < 4; ++di)
#pragma unroll
        for (int r = 0; r < 4; ++r) oacc[di][r] *= fr[r];
    }
#pragma unroll
    for (int ni = 0; ni < 4; ++ni)
#pragma unroll
      for (int r = 0; r < 4; ++r) {
        const float p = exp2f(sv[ni][r] - mrun[r]);
        lsum[r] += p;
        Pl[w][lg * 4 + r][ni * 16 + lo] = (_Float16)p;
      }
    const f16x8 pa0 = *(const f16x8*)(&Pl[w][lo][lg * 8]);
    const f16x8 pa1 = *(const f16x8*)(&Pl[w][lo][32 + lg * 8]);
    __builtin_amdgcn_s_setprio(1);
#pragma unroll
    for (int di = 0; di < 4; ++di) {
      const int d = di * 16 + lo;
      f16x8 vf0 = *(const f16x8*)(Vb + d * 64 + sl * 8);
      f16x8 vf1 = *(const f16x8*)(Vb + d * 64 + (sl ^ 4) * 8);
      oacc[di] = mfma16(pa0, vf0, oacc[di]);
      oacc[di] = mfma16(pa1, vf1, oacc[di]);
    }
    __builtin_amdgcn_s_setprio(0);
    __syncthreads();
  }

#pragma unroll
  for (int st = 1; st < 16; st <<= 1)
#pragma unroll
    for (int r = 0; r < 4; ++r) lsum[r] += __shfl_xor(lsum[r], st);

  if constexpr (NSPLIT > 1) {
    if (lo == 0) {
#pragma unroll
      for (int r = 0; r < 4; ++r)
        Sst[(size_t)sp * 65536 + bh * 1024 + qrow + r] = make_float2(mrun[r], lsum[r]);
    }
    _Float16* Op = (_Float16*)Oout + (size_t)sp * (64ull * 1024 * 64);
#pragma unroll
    for (int r = 0; r < 4; ++r) {
      const float inv = 1.0f / lsum[r];
#pragma unroll
      for (int di = 0; di < 4; ++di)
        Op[((size_t)bh * 1024 + qrow + r) * 64 + di * 16 + lo] =
            (_Float16)(oacc[di][r] * inv);
    }
  } else {
    _Float16* AO = (_Float16*)Oout;
#pragma unroll
    for (int r = 0; r < 4; ++r) {
      const float inv = 1.0f / lsum[r];
#pragma unroll
      for (int di = 0; di < 4; ++di)
        AO[((size_t)(b * 1024) + qrow + r) * 1024 + h * 64 + di * 16 + lo] =
            (_Float16)(oacc[di][r] * inv);
    }
  }
}

// keep the kernel set stable: force both instantiations
template __global__ void attn_kernel<1>(const _Float16*, const _Float16*,
                                        const _Float16*, const _Float16*,
                                        const float*, void*, float2*);
template __global__ void attn_kernel<2>(const _Float16*, const _Float16*,
                                        const _Float16*, const _Float16*,
                                        const float*, void*, float2*);

// ---------------- merge two KV-split partials -> AO (B,S,1024) ----------------
__global__ __launch_bounds__(256) void merge_kernel(
    const _Float16* __restrict__ Op, const float2* __restrict__ Sst,
    _Float16* __restrict__ AO) {
  const int idx = blockIdx.x * 256 + threadIdx.x;  // 1M threads, 4 d-elems each
  const int dc = idx & 15;
  const int qq = (idx >> 4) & 1023;
  const int bh = idx >> 14;
  const int b = bh >> 4, h = bh & 15;
  const float2 s1 = Sst[bh * 1024 + qq];
  const float2 s2 = Sst[65536 + bh * 1024 + qq];
  const float m = fmaxf(s1.x, s2.x);
  float w1 = exp2f(s1.x - m) * s1.y;
  float w2 = exp2f(s2.x - m) * s2.y;
  const float inv = 1.f / (w1 + w2);
  w1 *= inv; w2 *= inv;
  const size_t o = ((size_t)bh * 1024 + qq) * 64 + dc * 4;
  const f16x4 o1 = *(const f16x4*)(Op + o);
  const f16x4 o2 = *(const f16x4*)(Op + (64ull * 1024 * 64) + o);
  f16x4 r;
#pragma unroll
  for (int j = 0; j < 4; ++j)
    r[j] = (_Float16)(w1 * (float)o1[j] + w2 * (float)o2[j]);
  *(f16x4*)(AO + ((size_t)(b * 1024 + qq) * 1024 + h * 64 + dc * 4)) = r;
}

extern "C" void kernel_launch(void* const* d_in, const int* in_sizes, int n_in,
                              void* d_out, int out_size, void* d_ws, size_t ws_size,
                              hipStream_t stream) {
  (void)in_sizes; (void)n_in; (void)out_size;
  const float* v      = (const float*)d_in[0];
  const float* k      = (const float*)d_in[1];
  const float* q      = (const float*)d_in[2];
  const float* weight = (const float*)d_in[3];
  const float* mask   = (const float*)d_in[4];
  const float* Wq = (const float*)d_in[5];
  const float* bq = (const float*)d_in[6];
  const float* Wk = (const float*)d_in[7];
  const float* bk = (const float*)d_in[8];
  const float* Wv = (const float*)d_in[9];
  const float* bv = (const float*)d_in[10];
  const float* Wo = (const float*)d_in[11];
  const float* bo = (const float*)d_in[12];
  float* out = (float*)d_out;

  const size_t MB = 1ull << 20;
  char* ws = (char*)d_ws;
  _Float16* Wt = (_Float16*)ws;                 // 4 x 1M f16 = 8 MB
  _Float16* Qh = (_Float16*)(ws + 8 * MB);      // (B,H,S,64) f16, 8 MB
  _Float16* Kt = (_Float16*)(ws + 16 * MB);     // swizzled K tiles, 8 MB
  _Float16* Vt = (_Float16*)(ws + 24 * MB);     // swizzled V^T tiles, 8 MB
  _Float16* Wh = (_Float16*)(ws + 32 * MB);     // weight+mask f16 (q-major), 8 MB
  _Float16* Ah = (_Float16*)(ws + 40 * MB);     // f16 qkv, 24 MB (dead after proj)
  _Float16* AO = (_Float16*)(ws + 40 * MB);     // attn out, 8 MB (Ah dead by then)

  if (ws_size >= 64 * MB) {
    prep_kernel<<<12288, 256, 0, stream>>>(Wq, Wk, Wv, Wo, weight, mask, q, k, v,
                                           Wt, Wh, Ah);
    proj_kernel<true><<<dim3(8, 32, 3), 256, 0, stream>>>(Ah, q, k, v, Wt, bq, bk, bv,
                                                          Qh, Kt, Vt);
    attn_kernel<1><<<dim3(8, 64, 1), 512, 0, stream>>>(Qh, Kt, Vt, Wh, mask, AO, nullptr);
    outproj_kernel<<<dim3(8, 64), 256, 0, stream>>>(AO, Wt + 3 * (1 << 20), bo, out);
  } else {
    prep_kernel<<<6144, 256, 0, stream>>>(Wq, Wk, Wv, Wo, weight, mask, q, k, v,
                                          Wt, Wh, Ah);
    proj_kernel<false><<<dim3(8, 32, 3), 256, 0, stream>>>(nullptr, q, k, v, Wt, bq, bk,
                                                           bv, Qh, Kt, Vt);
    attn_kernel<1><<<dim3(8, 64, 1), 512, 0, stream>>>(Qh, Kt, Vt, Wh, mask, AO, nullptr);
    outproj_kernel<<<dim3(8, 64), 256, 0, stream>>>(AO, Wt + 3 * (1 << 20), bo, out);
  }
}